// Round 1
// baseline (10.960 us; speedup 1.0000x reference)
//
#include <hip/hip_runtime.h>
#include <hip/hip_bf16.h>

// ConceptEmbedding: out[b,s,:] = table[token_type[b,s]][concept[b,s], :] where
// table 1=proc, 2=med, 3=chart; zeros for token_type 0 (or any other value).
// B=16, S=2048, E=128, V=100000. Output f32 [B,S,E].
//
// Memory-bound gather. 32 lanes per position, one float4 (16B) per lane:
// gather reads and output stores are contiguous 512B per position.

__global__ __launch_bounds__(256) void concept_emb_kernel(
    const float* __restrict__ proc,
    const float* __restrict__ med,
    const float* __restrict__ chart,
    const int*   __restrict__ concept,
    const int*   __restrict__ ttype,
    float*       __restrict__ out,
    int npos) {
  int gid = blockIdx.x * blockDim.x + threadIdx.x;
  int pos = gid >> 5;          // one position per 32 lanes
  int j   = gid & 31;          // float4 index within the 128-float row
  if (pos >= npos) return;

  int t = ttype[pos];
  float4 v = make_float4(0.f, 0.f, 0.f, 0.f);
  if (t == 1 || t == 2 || t == 3) {
    const float* tab = (t == 1) ? proc : (t == 2) ? med : chart;
    long long c = concept[pos];
    v = *reinterpret_cast<const float4*>(tab + c * 128 + j * 4);
  }
  *reinterpret_cast<float4*>(out + (long long)pos * 128 + j * 4) = v;
}

extern "C" void kernel_launch(void* const* d_in, const int* in_sizes, int n_in,
                              void* d_out, int out_size, void* d_ws, size_t ws_size,
                              hipStream_t stream) {
  const float* proc    = (const float*)d_in[0];
  const float* med     = (const float*)d_in[1];
  const float* chart   = (const float*)d_in[2];
  const int*   concept = (const int*)d_in[3];
  const int*   ttype   = (const int*)d_in[4];
  float*       out     = (float*)d_out;

  const int npos = in_sizes[3];            // B*S = 32768
  const int threads = 256;
  const long long total = (long long)npos * 32;
  const int blocks = (int)((total + threads - 1) / threads);   // 4096

  concept_emb_kernel<<<blocks, threads, 0, stream>>>(
      proc, med, chart, concept, ttype, out, npos);
}